// Round 1
// baseline (501.478 us; speedup 1.0000x reference)
//
#include <hip/hip_runtime.h>
#include <cstddef>

// ---------------------------------------------------------------------------
// Fused attention block for MI355X (gfx950), FP16 MFMA pipeline.
// B=32, S=256, DIM=2048, NH=NKV=16, HD=128, GRID=16, BASE=10000, CLS=1.
//
// Pipeline:
//   1. cvt: x, wqkv, wo  f32 -> f16 (ws)
//   2. gemm_bt: qkv = x @ wqkv^T          (8192 x 6144 x 2048, f16 out)
//   3. rope: in-place 2D rope on q,k cols of qkv (pos 0 -> zeros, per ref)
//   4. attn: causal flash attention -> O f16 (8192 x 2048)
//   5. gemm_bt: out = O @ wo^T            (8192 x 2048 x 2048, f32 out)
//
// ws layout (160 MiB total):
//   [0,           100663296)  qkv f16  (8192*6144)
//   [100663296,   134217728)  x f16    (reused as O f16 after gemm1)
//   [134217728,   159383552)  wqkv f16
//   [159383552,   167772160)  wo f16
// ---------------------------------------------------------------------------

typedef float    f32x4 __attribute__((ext_vector_type(4)));
typedef _Float16 f16x8 __attribute__((ext_vector_type(8)));
typedef _Float16 f16x4 __attribute__((ext_vector_type(4)));

#define LOG2E 1.4426950408889634f

__device__ static inline f32x4 mfma16x32(f16x8 a, f16x8 b, f32x4 c) {
  return __builtin_amdgcn_mfma_f32_16x16x32_f16(a, b, c, 0, 0, 0);
}

// async global->LDS, 16B per lane; lds must be the wave-uniform base
// (HW dest = base + lane*16).
__device__ static inline void gload16(const void* g, void* lds) {
  __builtin_amdgcn_global_load_lds(
      (const __attribute__((address_space(1))) unsigned int*)g,
      (__attribute__((address_space(3))) unsigned int*)lds, 16, 0, 0);
}

// ---------------- 1. f32 -> f16 convert (vectorized) ----------------
__global__ void cvt_f32_f16(const float* __restrict__ src,
                            _Float16* __restrict__ dst, int n4) {
  int i = blockIdx.x * blockDim.x + threadIdx.x;
  if (i >= n4) return;
  f32x4 v = *(const f32x4*)(src + (size_t)i * 4);
  f16x4 o;
  o[0] = (_Float16)v[0]; o[1] = (_Float16)v[1];
  o[2] = (_Float16)v[2]; o[3] = (_Float16)v[3];
  *(f16x4*)(dst + (size_t)i * 4) = o;
}

// ---------------- 2./5. GEMM: C[m,n] = sum_k A[m,k] * Bt[n,k] ----------------
// 128x128 tile, BK=64, 4 waves, each wave a 64x64 quadrant (4x4 of 16x16).
// m97-style: global_load_lds dwordx4 staging, 2-barrier loop.
template <typename OutT>
__global__ void __launch_bounds__(256)
gemm_bt(const _Float16* __restrict__ A, const _Float16* __restrict__ Bt,
        OutT* __restrict__ C, int M, int N, int K) {
  __shared__ __attribute__((aligned(16))) _Float16 As[128 * 64];
  __shared__ __attribute__((aligned(16))) _Float16 Bs[128 * 64];
  const int tid  = threadIdx.x;
  const int lane = tid & 63;
  const int w    = tid >> 6;
  const int wr   = (w >> 1) << 6;   // wave row offset in tile
  const int wc   = (w & 1) << 6;    // wave col offset in tile
  const int g    = lane >> 4, li = lane & 15;
  const int nbn  = N >> 7;
  const int bm   = (int)(blockIdx.x / nbn) << 7;
  const int bn   = (int)(blockIdx.x % nbn) << 7;

  f32x4 acc[4][4] = {};
  const int srow = tid >> 3;   // staging row within 32-row issue
  const int sch  = tid & 7;    // staging 16B chunk within row

  for (int kt = 0; kt < K; kt += 64) {
#pragma unroll
    for (int i = 0; i < 4; ++i) {
      const _Float16* ga = A  + (size_t)(bm + i * 32 + srow) * K + kt + sch * 8;
      const _Float16* gb = Bt + (size_t)(bn + i * 32 + srow) * K + kt + sch * 8;
      const int lb = (i * 256 + (tid & 192)) * 16;   // wave-uniform byte base
      gload16(ga, (char*)As + lb);
      gload16(gb, (char*)Bs + lb);
    }
    __syncthreads();   // compiler drains vmcnt before barrier
#pragma unroll
    for (int kk = 0; kk < 2; ++kk) {
      f16x8 af[4], bq[4];
#pragma unroll
      for (int i = 0; i < 4; ++i) {
        af[i] = *(const f16x8*)((const char*)As + (wr + i * 16 + li) * 128 + kk * 64 + g * 16);
        bq[i] = *(const f16x8*)((const char*)Bs + (wc + i * 16 + li) * 128 + kk * 64 + g * 16);
      }
#pragma unroll
      for (int i = 0; i < 4; ++i)
#pragma unroll
        for (int j = 0; j < 4; ++j)
          acc[i][j] = mfma16x32(af[i], bq[j], acc[i][j]);
    }
    __syncthreads();
  }
  // epilogue: D row = (lane>>4)*4 + r, col = lane&15 (m89-verified layout)
#pragma unroll
  for (int i = 0; i < 4; ++i)
#pragma unroll
    for (int j = 0; j < 4; ++j)
#pragma unroll
      for (int r = 0; r < 4; ++r) {
        const int row = bm + wr + i * 16 + g * 4 + r;
        const int col = bn + wc + j * 16 + li;
        if constexpr (sizeof(OutT) == 2)
          C[(size_t)row * N + col] = (OutT)acc[i][j][r];
        else
          C[(size_t)row * N + col] = acc[i][j][r];
      }
}

// ---------------- 3. RoPE (2D, grid 16x16, cls offset 1) ----------------
// qkv cols [0,4096) = q heads 0..15 then k heads 0..15 (each 128 wide).
// pair d (0..63): angle = t_sel * base^(-(d&31)/32), t_sel = row(i) for d<32
// else col(j), with i=(p-1)/16, j=(p-1)%16.  p==0 -> cos=sin=0 -> output 0.
__global__ void rope_kernel(_Float16* __restrict__ qkv,
                            const int* __restrict__ positions) {
  const int idx = blockIdx.x * blockDim.x + threadIdx.x;  // t*512 + hh*16 + ch
  const int ch = idx & 15;          // 16B chunk (4 pairs) within head
  const int hh = (idx >> 4) & 31;   // 0..15 q-heads, 16..31 k-heads
  const int t  = idx >> 9;
  _Float16* p = qkv + (size_t)t * 6144 + hh * 128 + ch * 8;
  const int pos = positions[t];
  f16x8 v = *(const f16x8*)p;
  f16x8 o;
  if (pos == 0) {
#pragma unroll
    for (int u = 0; u < 8; ++u) o[u] = (_Float16)0.f;
  } else {
    const int gi = pos - 1;
    const float tv = (ch < 8) ? (float)(gi >> 4) : (float)(gi & 15);
#pragma unroll
    for (int u = 0; u < 4; ++u) {
      const int k2 = (ch * 4 + u) & 31;
      const float freq = exp2f((float)k2 * (-13.287712379549449f / 32.0f));
      const float ang = tv * freq;
      float s, c;
      sincosf(ang, &s, &c);
      const float x0 = (float)v[2 * u];
      const float x1 = (float)v[2 * u + 1];
      o[2 * u]     = (_Float16)(x0 * c - x1 * s);
      o[2 * u + 1] = (_Float16)(x1 * c + x0 * s);
    }
  }
  *(f16x8*)p = o;
}

// ---------------- 4. causal flash attention ----------------
// 1 block = 1 (b,h), 512 threads = 8 waves, wave w owns q rows [32w,32w+32).
// K-tiles of 64 keys staged in LDS:
//   Ks: row-major [64][128], 16B chunks XOR-swizzled (chunk ^= key&7) via
//       pre-swizzled global source (global_load_lds writes linearly).
//   Vt: transposed [d][key] with chunk swizzle blk = (key>>3)^(d&7)^((d>>3)&7).
//   Ps: per-wave P round-trip (D-frag layout -> A-frag layout), stride 40.
__global__ void __launch_bounds__(512)
attn_kernel(const _Float16* __restrict__ qkv, _Float16* __restrict__ O) {
  const int b  = blockIdx.x >> 4;
  const int h  = blockIdx.x & 15;
  const int tb = b << 8;
  const int tid = threadIdx.x;
  const int lane = tid & 63;
  const int w = tid >> 6;
  const int g = lane >> 4, li = lane & 15;

  __shared__ __attribute__((aligned(16))) _Float16 Ks[64 * 128];
  __shared__ __attribute__((aligned(16))) _Float16 Vt[128 * 64];
  __shared__ __attribute__((aligned(16))) _Float16 Ps[8][32 * 40];

  // Q fragments: rows 32w+16rb+li, k-chunk g*8 within 32-wide k-step ks
  f16x8 qf[2][4];
#pragma unroll
  for (int rb = 0; rb < 2; ++rb)
#pragma unroll
    for (int ks = 0; ks < 4; ++ks)
      qf[rb][ks] = *(const f16x8*)(qkv + (size_t)(tb + w * 32 + rb * 16 + li) * 6144
                                   + h * 128 + ks * 32 + g * 8);

  f32x4 oacc[2][8] = {};
  float m_r[2][4], l_r[2][4];
#pragma unroll
  for (int rb = 0; rb < 2; ++rb)
#pragma unroll
    for (int r = 0; r < 4; ++r) { m_r[rb][r] = -1e30f; l_r[rb][r] = 0.f; }

  const float scale = 0.08838834764831845f;  // 1/sqrt(128)

  for (int kt = 0; kt < 4; ++kt) {
    // ---- stage K tile (source-swizzled so LDS holds chunk^(key&7)) ----
#pragma unroll
    for (int i = 0; i < 2; ++i) {
      const int s = i * 512 + tid;
      const int key = s >> 4;
      const int sch = (s & 15) ^ (key & 7);
      const _Float16* gk = qkv + (size_t)(tb + kt * 64 + key) * 6144
                           + 2048 + h * 128 + sch * 8;
      gload16(gk, (char*)Ks + (i * 512 + (tid & ~63)) * 16);
    }
    // ---- stage V transposed + swizzled via registers ----
#pragma unroll
    for (int i = 0; i < 2; ++i) {
      const int s = i * 512 + tid;
      const int key = s >> 4;
      const int chv = s & 15;
      f16x8 v = *(const f16x8*)(qkv + (size_t)(tb + kt * 64 + key) * 6144
                                + 4096 + h * 128 + chv * 8);
#pragma unroll
      for (int e = 0; e < 8; ++e) {
        const int d = chv * 8 + e;
        const int blk = ((key >> 3) ^ (d & 7) ^ ((d >> 3) & 7)) & 7;
        Vt[d * 64 + blk * 8 + (key & 7)] = v[e];
      }
    }
    __syncthreads();

    if (kt <= (w >> 1)) {   // causal: this wave needs this k-tile
      // ---- S = Q K^T (64 keys) ----
      f32x4 sacc[2][4] = {};
#pragma unroll
      for (int ks = 0; ks < 4; ++ks) {
        f16x8 kf[4];
#pragma unroll
        for (int cb = 0; cb < 4; ++cb) {
          const int key = cb * 16 + li;
          const int chunk = (ks * 4 + g) ^ (key & 7);
          kf[cb] = *(const f16x8*)((const char*)Ks + key * 256 + chunk * 16);
        }
#pragma unroll
        for (int rb = 0; rb < 2; ++rb)
#pragma unroll
          for (int cb = 0; cb < 4; ++cb)
            sacc[rb][cb] = mfma16x32(qf[rb][ks], kf[cb], sacc[rb][cb]);
      }
      // ---- online softmax (wave-parallel, 16-lane-group shfl reduce) ----
#pragma unroll
      for (int rb = 0; rb < 2; ++rb) {
#pragma unroll
        for (int r = 0; r < 4; ++r) {
          const int q = w * 32 + rb * 16 + g * 4 + r;
          float mx = -1e30f;
#pragma unroll
          for (int cb = 0; cb < 4; ++cb) {
            float sv = sacc[rb][cb][r] * scale;
            const int key = kt * 64 + cb * 16 + li;
            sv = (key <= q) ? sv : -1e30f;
            sacc[rb][cb][r] = sv;
            mx = fmaxf(mx, sv);
          }
#pragma unroll
          for (int off = 1; off < 16; off <<= 1)
            mx = fmaxf(mx, __shfl_xor(mx, off));
          const float mold = m_r[rb][r];
          const float mnew = fmaxf(mold, mx);
          const float alpha = exp2f((mold - mnew) * LOG2E);
          float rsum = 0.f;
#pragma unroll
          for (int cb = 0; cb < 4; ++cb) {
            const float pv = exp2f((sacc[rb][cb][r] - mnew) * LOG2E);
            sacc[rb][cb][r] = pv;
            rsum += pv;
          }
#pragma unroll
          for (int off = 1; off < 16; off <<= 1)
            rsum += __shfl_xor(rsum, off);
          m_r[rb][r] = mnew;
          l_r[rb][r] = l_r[rb][r] * alpha + rsum;
#pragma unroll
          for (int db = 0; db < 8; ++db)
            oacc[rb][db][r] *= alpha;
        }
      }
      // ---- O += P V, in two 32-key halves (P relayout via per-wave LDS) ----
#pragma unroll
      for (int ks2 = 0; ks2 < 2; ++ks2) {
#pragma unroll
        for (int rb = 0; rb < 2; ++rb)
#pragma unroll
          for (int cbh = 0; cbh < 2; ++cbh) {
            const int cb = ks2 * 2 + cbh;
#pragma unroll
            for (int r = 0; r < 4; ++r)
              Ps[w][(rb * 16 + g * 4 + r) * 40 + cbh * 16 + li] =
                  (_Float16)sacc[rb][cb][r];
          }
        asm volatile("s_waitcnt lgkmcnt(0)" ::: "memory");
        f16x8 pa[2];
#pragma unroll
        for (int rb = 0; rb < 2; ++rb)
          pa[rb] = *(const f16x8*)(&Ps[w][(rb * 16 + li) * 40 + g * 8]);
#pragma unroll
        for (int db = 0; db < 8; ++db) {
          const int d = db * 16 + li;
          const int keych = ks2 * 4 + g;
          const int blk = (keych ^ (d & 7) ^ ((d >> 3) & 7)) & 7;
          const f16x8 vf = *(const f16x8*)(&Vt[d * 64 + blk * 8]);
#pragma unroll
          for (int rb = 0; rb < 2; ++rb)
            oacc[rb][db] = mfma16x32(pa[rb], vf, oacc[rb][db]);
        }
      }
    }
    __syncthreads();
  }
  // ---- epilogue: O / l ----
#pragma unroll
  for (int rb = 0; rb < 2; ++rb)
#pragma unroll
    for (int db = 0; db < 8; ++db)
#pragma unroll
      for (int r = 0; r < 4; ++r) {
        const int row = tb + w * 32 + rb * 16 + g * 4 + r;
        const int col = h * 128 + db * 16 + li;
        O[(size_t)row * 2048 + col] = (_Float16)(oacc[rb][db][r] / l_r[rb][r]);
      }
}

// ---------------------------------------------------------------------------
extern "C" void kernel_launch(void* const* d_in, const int* in_sizes, int n_in,
                              void* d_out, int out_size, void* d_ws, size_t ws_size,
                              hipStream_t stream) {
  const float* x         = (const float*)d_in[0];
  const int*   positions = (const int*)d_in[1];
  const float* wqkv      = (const float*)d_in[2];
  const float* wo        = (const float*)d_in[3];
  float* out = (float*)d_out;

  char* ws = (char*)d_ws;
  _Float16* qkv    = (_Float16*)(ws);                    // 100663296 B
  _Float16* xf     = (_Float16*)(ws + 100663296);        //  33554432 B
  _Float16* wqkvf  = (_Float16*)(ws + 134217728);        //  25165824 B
  _Float16* wof    = (_Float16*)(ws + 159383552);        //   8388608 B
  _Float16* of     = xf;  // reuse x region for attention output

  cvt_f32_f16<<<16384, 256, 0, stream>>>(x, xf, 4194304);
  cvt_f32_f16<<<12288, 256, 0, stream>>>(wqkv, wqkvf, 3145728);
  cvt_f32_f16<<< 4096, 256, 0, stream>>>(wo, wof, 1048576);

  gemm_bt<_Float16><<<3072, 256, 0, stream>>>(xf, wqkvf, qkv, 8192, 6144, 2048);

  rope_kernel<<<16384, 256, 0, stream>>>(qkv, positions);

  attn_kernel<<<512, 512, 0, stream>>>(qkv, of);

  gemm_bt<float><<<1024, 256, 0, stream>>>(of, wof, out, 8192, 2048, 2048);
}

// Round 2
// 440.946 us; speedup vs baseline: 1.1373x; 1.1373x over previous
//
#include <hip/hip_runtime.h>
#include <cstddef>

// ---------------------------------------------------------------------------
// Fused attention block for MI355X (gfx950), FP16 MFMA pipeline.
// B=32, S=256, DIM=2048, NH=NKV=16, HD=128, GRID=16, BASE=10000, CLS=1.
//
// Pipeline:
//   1. cvt: x, wqkv, wo  f32 -> f16 (ws)
//   2. gemm_bt2: qkv = x @ wqkv^T          (8192 x 6144 x 2048, f16 out)
//   3. rope: in-place 2D rope on q,k cols of qkv (pos 0 -> zeros, per ref)
//   4. attn: causal flash attention -> O f16 (8192 x 2048)
//   5. gemm_bt2: out = O @ wo^T            (8192 x 2048 x 2048, f32 out)
//
// gemm_bt2: 256x256 tile, BK=32, 512 thr / 8 waves (2m x 4n), 3 LDS buffers,
// counted-vmcnt pipeline (T3+T4), XOR-swizzled LDS (T2), setprio (T5),
// XCD-aware block swizzle (T1).
// ---------------------------------------------------------------------------

typedef float    f32x4 __attribute__((ext_vector_type(4)));
typedef _Float16 f16x8 __attribute__((ext_vector_type(8)));
typedef _Float16 f16x4 __attribute__((ext_vector_type(4)));

#define LOG2E 1.4426950408889634f

__device__ static inline f32x4 mfma16x32(f16x8 a, f16x8 b, f32x4 c) {
  return __builtin_amdgcn_mfma_f32_16x16x32_f16(a, b, c, 0, 0, 0);
}

// async global->LDS, 16B per lane; lds must be the wave-uniform base
// (HW dest = base + lane*16).
__device__ static inline void gload16(const void* g, void* lds) {
  __builtin_amdgcn_global_load_lds(
      (const __attribute__((address_space(1))) unsigned int*)g,
      (__attribute__((address_space(3))) unsigned int*)lds, 16, 0, 0);
}

// ---------------- 1. f32 -> f16 convert (vectorized) ----------------
__global__ void cvt_f32_f16(const float* __restrict__ src,
                            _Float16* __restrict__ dst, int n4) {
  int i = blockIdx.x * blockDim.x + threadIdx.x;
  if (i >= n4) return;
  f32x4 v = *(const f32x4*)(src + (size_t)i * 4);
  f16x4 o;
  o[0] = (_Float16)v[0]; o[1] = (_Float16)v[1];
  o[2] = (_Float16)v[2]; o[3] = (_Float16)v[3];
  *(f16x4*)(dst + (size_t)i * 4) = o;
}

// ---------------- 2./5. GEMM: C[m,n] = sum_k A[m,k] * Bt[n,k] ----------------
// 256x256 tile, BK=32. 8 waves: wm = w>>2 (2), wn = w&3 (4); per-wave out
// 128x64 = 8x4 frags of 16x16. LDS: 3 buffers x (A 256x32 + B 256x32) f16
// = 96 KiB. Swizzle: 16B chunk c stored at c ^ ((row>>1)&3)  (2-way max on
// ds_read_b128, free per m136). Pipeline: tile T computes from buf[T%3];
// stages tile T+2 into buf[(T+2)%3] (= tile T-1's buffer, reads long done);
// one vmcnt(4)+barrier per tile (4 loads of T+2 stay in flight).
template <typename OutT>
__global__ void __launch_bounds__(512, 2)
gemm_bt2(const _Float16* __restrict__ A, const _Float16* __restrict__ Bt,
         OutT* __restrict__ C, int M, int N, int K) {
  __shared__ __attribute__((aligned(16))) _Float16 Ab[3][256 * 32];
  __shared__ __attribute__((aligned(16))) _Float16 Bb[3][256 * 32];

  const int tid  = threadIdx.x;
  const int lane = tid & 63;
  const int w    = tid >> 6;
  const int wm   = w >> 2, wn = w & 3;
  const int g    = lane >> 4, li = lane & 15;

  // T1: XCD-aware block swizzle (grid is a multiple of 8 for our shapes)
  const int nwg = (int)gridDim.x;
  const int cpx = nwg >> 3;
  const int bid = (int)blockIdx.x;
  const int swz = (bid & 7) * cpx + (bid >> 3);
  const int nbn = N >> 8;
  const int bm  = (swz / nbn) << 8;
  const int bn  = (swz % nbn) << 8;

  const int NT = K >> 5;   // 32-wide K tiles

  // ---- staging addressing (per thread: one 16B chunk, 2 row-halves/issue) --
  const int srow = tid >> 2;                       // 0..127 within half
  const int csrc = (lane & 3) ^ ((lane >> 3) & 3); // pre-swizzled source chunk
  const _Float16* gA = A  + (size_t)(bm + srow) * K + csrc * 8;
  const _Float16* gB = Bt + (size_t)(bn + srow) * K + csrc * 8;
  const int ldsW = w * 512;                        // wave-uniform base (elems)

  auto stageA = [&](int bufi, int kt) {
#pragma unroll
    for (int i = 0; i < 2; ++i)
      gload16(gA + (size_t)i * 128 * K + kt, &Ab[bufi][i * 4096 + ldsW]);
  };
  auto stageB = [&](int bufi, int kt) {
#pragma unroll
    for (int i = 0; i < 2; ++i)
      gload16(gB + (size_t)i * 128 * K + kt, &Bb[bufi][i * 4096 + ldsW]);
  };

  // ---- fragment read addressing ----
  const int rchunk = (g ^ ((li >> 1) & 3)) * 8;  // swizzled k-chunk (elems)
  const int arow0  = wm * 128 + li;
  const int brow0  = wn * 64 + li;

  f32x4 acc[8][4] = {};

  // ---- prologue: tiles 0,1 in flight; wait for tile 0 ----
  stageA(0, 0);  stageB(0, 0);
  stageA(1, 32); stageB(1, 32);
  asm volatile("s_waitcnt vmcnt(4)" ::: "memory");
  __builtin_amdgcn_s_barrier();

  int cur = 0;
  for (int T = 0; T < NT; ++T) {
    const int nxt = (cur == 2) ? 0 : cur + 1;
    const int nx2 = (nxt == 2) ? 0 : nxt + 1;
    const int ktp = (T + 2 < NT) ? (T + 2) * 32 : 0;  // clamped prefetch

    // -- h0: stage A(T+2); read A frags + B frags n0,n1; 16 MFMA --
    stageA(nx2, ktp);
    f16x8 af[8], bf[4];
#pragma unroll
    for (int m = 0; m < 8; ++m)
      af[m] = *(const f16x8*)&Ab[cur][(arow0 + m * 16) * 32 + rchunk];
#pragma unroll
    for (int n = 0; n < 2; ++n)
      bf[n] = *(const f16x8*)&Bb[cur][(brow0 + n * 16) * 32 + rchunk];
    __builtin_amdgcn_s_setprio(1);
#pragma unroll
    for (int m = 0; m < 8; ++m)
#pragma unroll
      for (int n = 0; n < 2; ++n)
        acc[m][n] = mfma16x32(af[m], bf[n], acc[m][n]);
    __builtin_amdgcn_s_setprio(0);

    // -- h1: stage B(T+2); read B frags n2,n3; 16 MFMA --
    stageB(nx2, ktp);
#pragma unroll
    for (int n = 2; n < 4; ++n)
      bf[n] = *(const f16x8*)&Bb[cur][(brow0 + n * 16) * 32 + rchunk];
    __builtin_amdgcn_s_setprio(1);
#pragma unroll
    for (int m = 0; m < 8; ++m)
#pragma unroll
      for (int n = 2; n < 4; ++n)
        acc[m][n] = mfma16x32(af[m], bf[n], acc[m][n]);
    __builtin_amdgcn_s_setprio(0);

    // -- gate: tile T+1 landed; tile T+2's 4 loads stay in flight --
    asm volatile("s_waitcnt vmcnt(4)" ::: "memory");
    __builtin_amdgcn_s_barrier();
    __builtin_amdgcn_sched_barrier(0);
    cur = nxt;
  }

  // ---- epilogue: D row = g*4+r, col = li (m89-verified layout) ----
#pragma unroll
  for (int m = 0; m < 8; ++m)
#pragma unroll
    for (int n = 0; n < 4; ++n)
#pragma unroll
      for (int r = 0; r < 4; ++r) {
        const int row = bm + wm * 128 + m * 16 + g * 4 + r;
        const int col = bn + wn * 64 + n * 16 + li;
        C[(size_t)row * N + col] = (OutT)acc[m][n][r];
      }
}

// ---------------- 3. RoPE (2D, grid 16x16, cls offset 1) ----------------
__global__ void rope_kernel(_Float16* __restrict__ qkv,
                            const int* __restrict__ positions) {
  const int idx = blockIdx.x * blockDim.x + threadIdx.x;  // t*512 + hh*16 + ch
  const int ch = idx & 15;          // 16B chunk (4 pairs) within head
  const int hh = (idx >> 4) & 31;   // 0..15 q-heads, 16..31 k-heads
  const int t  = idx >> 9;
  _Float16* p = qkv + (size_t)t * 6144 + hh * 128 + ch * 8;
  const int pos = positions[t];
  f16x8 v = *(const f16x8*)p;
  f16x8 o;
  if (pos == 0) {
#pragma unroll
    for (int u = 0; u < 8; ++u) o[u] = (_Float16)0.f;
  } else {
    const int gi = pos - 1;
    const float tv = (ch < 8) ? (float)(gi >> 4) : (float)(gi & 15);
#pragma unroll
    for (int u = 0; u < 4; ++u) {
      const int k2 = (ch * 4 + u) & 31;
      const float freq = exp2f((float)k2 * (-13.287712379549449f / 32.0f));
      const float ang = tv * freq;
      float s, c;
      sincosf(ang, &s, &c);
      const float x0 = (float)v[2 * u];
      const float x1 = (float)v[2 * u + 1];
      o[2 * u]     = (_Float16)(x0 * c - x1 * s);
      o[2 * u + 1] = (_Float16)(x1 * c + x0 * s);
    }
  }
  *(f16x8*)p = o;
}

// ---------------- 4. causal flash attention ----------------
__global__ void __launch_bounds__(512)
attn_kernel(const _Float16* __restrict__ qkv, _Float16* __restrict__ O) {
  const int b  = blockIdx.x >> 4;
  const int h  = blockIdx.x & 15;
  const int tb = b << 8;
  const int tid = threadIdx.x;
  const int lane = tid & 63;
  const int w = tid >> 6;
  const int g = lane >> 4, li = lane & 15;

  __shared__ __attribute__((aligned(16))) _Float16 Ks[64 * 128];
  __shared__ __attribute__((aligned(16))) _Float16 Vt[128 * 64];
  __shared__ __attribute__((aligned(16))) _Float16 Ps[8][32 * 40];

  f16x8 qf[2][4];
#pragma unroll
  for (int rb = 0; rb < 2; ++rb)
#pragma unroll
    for (int ks = 0; ks < 4; ++ks)
      qf[rb][ks] = *(const f16x8*)(qkv + (size_t)(tb + w * 32 + rb * 16 + li) * 6144
                                   + h * 128 + ks * 32 + g * 8);

  f32x4 oacc[2][8] = {};
  float m_r[2][4], l_r[2][4];
#pragma unroll
  for (int rb = 0; rb < 2; ++rb)
#pragma unroll
    for (int r = 0; r < 4; ++r) { m_r[rb][r] = -1e30f; l_r[rb][r] = 0.f; }

  const float scale = 0.08838834764831845f;  // 1/sqrt(128)

  for (int kt = 0; kt < 4; ++kt) {
#pragma unroll
    for (int i = 0; i < 2; ++i) {
      const int s = i * 512 + tid;
      const int key = s >> 4;
      const int sch = (s & 15) ^ (key & 7);
      const _Float16* gk = qkv + (size_t)(tb + kt * 64 + key) * 6144
                           + 2048 + h * 128 + sch * 8;
      gload16(gk, (char*)Ks + (i * 512 + (tid & ~63)) * 16);
    }
#pragma unroll
    for (int i = 0; i < 2; ++i) {
      const int s = i * 512 + tid;
      const int key = s >> 4;
      const int chv = s & 15;
      f16x8 v = *(const f16x8*)(qkv + (size_t)(tb + kt * 64 + key) * 6144
                                + 4096 + h * 128 + chv * 8);
#pragma unroll
      for (int e = 0; e < 8; ++e) {
        const int d = chv * 8 + e;
        const int blk = ((key >> 3) ^ (d & 7) ^ ((d >> 3) & 7)) & 7;
        Vt[d * 64 + blk * 8 + (key & 7)] = v[e];
      }
    }
    __syncthreads();

    if (kt <= (w >> 1)) {
      f32x4 sacc[2][4] = {};
#pragma unroll
      for (int ks = 0; ks < 4; ++ks) {
        f16x8 kf[4];
#pragma unroll
        for (int cb = 0; cb < 4; ++cb) {
          const int key = cb * 16 + li;
          const int chunk = (ks * 4 + g) ^ (key & 7);
          kf[cb] = *(const f16x8*)((const char*)Ks + key * 256 + chunk * 16);
        }
#pragma unroll
        for (int rb = 0; rb < 2; ++rb)
#pragma unroll
          for (int cb = 0; cb < 4; ++cb)
            sacc[rb][cb] = mfma16x32(qf[rb][ks], kf[cb], sacc[rb][cb]);
      }
#pragma unroll
      for (int rb = 0; rb < 2; ++rb) {
#pragma unroll
        for (int r = 0; r < 4; ++r) {
          const int q = w * 32 + rb * 16 + g * 4 + r;
          float mx = -1e30f;
#pragma unroll
          for (int cb = 0; cb < 4; ++cb) {
            float sv = sacc[rb][cb][r] * scale;
            const int key = kt * 64 + cb * 16 + li;
            sv = (key <= q) ? sv : -1e30f;
            sacc[rb][cb][r] = sv;
            mx = fmaxf(mx, sv);
          }
#pragma unroll
          for (int off = 1; off < 16; off <<= 1)
            mx = fmaxf(mx, __shfl_xor(mx, off));
          const float mold = m_r[rb][r];
          const float mnew = fmaxf(mold, mx);
          const float alpha = exp2f((mold - mnew) * LOG2E);
          float rsum = 0.f;
#pragma unroll
          for (int cb = 0; cb < 4; ++cb) {
            const float pv = exp2f((sacc[rb][cb][r] - mnew) * LOG2E);
            sacc[rb][cb][r] = pv;
            rsum += pv;
          }
#pragma unroll
          for (int off = 1; off < 16; off <<= 1)
            rsum += __shfl_xor(rsum, off);
          m_r[rb][r] = mnew;
          l_r[rb][r] = l_r[rb][r] * alpha + rsum;
#pragma unroll
          for (int db = 0; db < 8; ++db)
            oacc[rb][db][r] *= alpha;
        }
      }
#pragma unroll
      for (int ks2 = 0; ks2 < 2; ++ks2) {
#pragma unroll
        for (int rb = 0; rb < 2; ++rb)
#pragma unroll
          for (int cbh = 0; cbh < 2; ++cbh) {
            const int cb = ks2 * 2 + cbh;
#pragma unroll
            for (int r = 0; r < 4; ++r)
              Ps[w][(rb * 16 + g * 4 + r) * 40 + cbh * 16 + li] =
                  (_Float16)sacc[rb][cb][r];
          }
        asm volatile("s_waitcnt lgkmcnt(0)" ::: "memory");
        f16x8 pa[2];
#pragma unroll
        for (int rb = 0; rb < 2; ++rb)
          pa[rb] = *(const f16x8*)(&Ps[w][(rb * 16 + li) * 40 + g * 8]);
#pragma unroll
        for (int db = 0; db < 8; ++db) {
          const int d = db * 16 + li;
          const int keych = ks2 * 4 + g;
          const int blk = (keych ^ (d & 7) ^ ((d >> 3) & 7)) & 7;
          const f16x8 vf = *(const f16x8*)(&Vt[d * 64 + blk * 8]);
#pragma unroll
          for (int rb = 0; rb < 2; ++rb)
            oacc[rb][db] = mfma16x32(pa[rb], vf, oacc[rb][db]);
        }
      }
    }
    __syncthreads();
  }
#pragma unroll
  for (int rb = 0; rb < 2; ++rb)
#pragma unroll
    for (int db = 0; db < 8; ++db)
#pragma unroll
      for (int r = 0; r < 4; ++r) {
        const int row = tb + w * 32 + rb * 16 + g * 4 + r;
        const int col = h * 128 + db * 16 + li;
        O[(size_t)row * 2048 + col] = (_Float16)(oacc[rb][db][r] / l_r[rb][r]);
      }
}

// ---------------------------------------------------------------------------
extern "C" void kernel_launch(void* const* d_in, const int* in_sizes, int n_in,
                              void* d_out, int out_size, void* d_ws, size_t ws_size,
                              hipStream_t stream) {
  const float* x         = (const float*)d_in[0];
  const int*   positions = (const int*)d_in[1];
  const float* wqkv      = (const float*)d_in[2];
  const float* wo        = (const float*)d_in[3];
  float* out = (float*)d_out;

  char* ws = (char*)d_ws;
  _Float16* qkv    = (_Float16*)(ws);                    // 100663296 B
  _Float16* xf     = (_Float16*)(ws + 100663296);        //  33554432 B
  _Float16* wqkvf  = (_Float16*)(ws + 134217728);        //  25165824 B
  _Float16* wof    = (_Float16*)(ws + 159383552);        //   8388608 B
  _Float16* of     = xf;  // reuse x region for attention output

  cvt_f32_f16<<<16384, 256, 0, stream>>>(x, xf, 4194304);
  cvt_f32_f16<<<12288, 256, 0, stream>>>(wqkv, wqkvf, 3145728);
  cvt_f32_f16<<< 4096, 256, 0, stream>>>(wo, wof, 1048576);

  gemm_bt2<_Float16><<<768, 512, 0, stream>>>(xf, wqkvf, qkv, 8192, 6144, 2048);

  rope_kernel<<<16384, 256, 0, stream>>>(qkv, positions);

  attn_kernel<<<512, 512, 0, stream>>>(qkv, of);

  gemm_bt2<float><<<256, 512, 0, stream>>>(of, wof, out, 8192, 2048, 2048);
}

// Round 3
// 382.140 us; speedup vs baseline: 1.3123x; 1.1539x over previous
//
#include <hip/hip_runtime.h>
#include <cstddef>

// ---------------------------------------------------------------------------
// Fused attention block for MI355X (gfx950), FP16 MFMA pipeline.
// B=32, S=256, DIM=2048, NH=NKV=16, HD=128, GRID=16, BASE=10000, CLS=1.
//
// Pipeline:
//   1. cvt: x, wqkv, wo  f32 -> f16 (ws)
//   2. gemm_bt3: qkv = x @ wqkv^T          (8192 x 6144 x 2048, f16 out)
//   3. rope: in-place 2D rope on q,k cols of qkv (pos 0 -> zeros, per ref)
//   4. attn: causal flash attention -> O f16 (8192 x 2048)
//   5. gemm_bt3: out = O @ wo^T            (8192 x 2048 x 2048, f32 out)
//
// gemm_bt3 = m201-style 8-phase schedule: 256x256 tile, BK=64, 8 waves
// (2m x 4n), 2-deep LDS double buffer (128 KiB), 4 phases per K-tile with
// 16 MFMA each, per-phase half-tile staging (stage -> first-use distance =
// 4 phases), uniform counted s_waitcnt vmcnt(6) before each closing barrier,
// XOR chunk swizzle c^(r&7) (conflict-free b128), setprio around MFMA,
// XCD-aware block swizzle.
// ---------------------------------------------------------------------------

typedef float    f32x4 __attribute__((ext_vector_type(4)));
typedef _Float16 f16x8 __attribute__((ext_vector_type(8)));
typedef _Float16 f16x4 __attribute__((ext_vector_type(4)));

#define LOG2E 1.4426950408889634f

__device__ static inline f32x4 mfma16x32(f16x8 a, f16x8 b, f32x4 c) {
  return __builtin_amdgcn_mfma_f32_16x16x32_f16(a, b, c, 0, 0, 0);
}

// async global->LDS, 16B per lane; lds must be the wave-uniform base
// (HW dest = base + lane*16).
__device__ static inline void gload16(const void* g, void* lds) {
  __builtin_amdgcn_global_load_lds(
      (const __attribute__((address_space(1))) unsigned int*)g,
      (__attribute__((address_space(3))) unsigned int*)lds, 16, 0, 0);
}

#define BAR()    asm volatile("s_barrier" ::: "memory")
#define VMCNT6() asm volatile("s_waitcnt vmcnt(6)" ::: "memory")

// ---------------- 1. f32 -> f16 convert (vectorized) ----------------
__global__ void cvt_f32_f16(const float* __restrict__ src,
                            _Float16* __restrict__ dst, int n4) {
  int i = blockIdx.x * blockDim.x + threadIdx.x;
  if (i >= n4) return;
  f32x4 v = *(const f32x4*)(src + (size_t)i * 4);
  f16x4 o;
  o[0] = (_Float16)v[0]; o[1] = (_Float16)v[1];
  o[2] = (_Float16)v[2]; o[3] = (_Float16)v[3];
  *(f16x4*)(dst + (size_t)i * 4) = o;
}

// ---------------- 2./5. GEMM: C[m,n] = sum_k A[m,k] * Bt[n,k] ----------------
// Per K-tile (BK=64) 4 phases, per phase one C-quadrant (16 MFMA):
//   p0: read af0(8) bf0(4); stage B0(T+1); MFMA af0 x bf0
//   p1: read bf1(4);        stage B1(T+1); MFMA af0 x bf1
//   p2: read af1(8);        stage A1(T+1); MFMA af1 x bf0
//   p3: (no reads)          stage A0(T+2); MFMA af1 x bf1
// Each phase: reads; stage; BAR; setprio(1); MFMA; setprio(0); vmcnt(6); BAR.
// Gate proof: at each closing vmcnt(6) the 3 newest half-tiles (6 loads) may
// be outstanding; every half-tile a phase reads is >= 4th-newest there.
template <typename OutT>
__global__ void __launch_bounds__(512, 2)
gemm_bt3(const _Float16* __restrict__ A, const _Float16* __restrict__ Bt,
         OutT* __restrict__ C, int M, int N, int K) {
  __shared__ __attribute__((aligned(16))) _Float16 Ab[2][256 * 64];
  __shared__ __attribute__((aligned(16))) _Float16 Bb[2][256 * 64];

  const int tid  = threadIdx.x;
  const int lane = tid & 63;
  const int w    = tid >> 6;
  const int wm   = w >> 2, wn = w & 3;
  const int g    = lane >> 4, li = lane & 15;

  // T1: XCD-aware block swizzle (grid multiple of 8 for our shapes)
  const int nwg = (int)gridDim.x;
  const int cpx = nwg >> 3;
  const int bid = (int)blockIdx.x;
  const int swz = (bid & 7) * cpx + (bid >> 3);
  const int nbn = N >> 8;
  const int bm  = (swz / nbn) << 8;
  const int bn  = (swz % nbn) << 8;
  const int NT  = K >> 6;

  // ---- staging: half-tile = 128 rows x 64 cols = 1024 chunks of 16B.
  // Thread t, load j covers linear chunk L = j*512 + t  (row L>>3, phys L&7),
  // holding logical chunk (L&7)^((L>>3)&7) -> global col ((t&7)^((t>>3)&7))*8.
  const int srow = tid >> 3;                       // 0..63
  const int scol = ((tid & 7) ^ (srow & 7)) * 8;   // pre-swizzled col (elems)
  const _Float16* gA = A  + (size_t)(bm + srow) * K + scol;
  const _Float16* gB = Bt + (size_t)(bn + srow) * K + scol;
  const int sdst = w * 1024;                       // wave-uniform byte base

  auto stage = [&](const _Float16* gbase, _Float16* lbase, int h, int kt) {
    const _Float16* gp = gbase + (size_t)h * 128 * K + kt;
    char* lp = (char*)lbase + h * 16384;
#pragma unroll
    for (int j = 0; j < 2; ++j)
      gload16(gp + (size_t)j * 64 * K, lp + j * 8192 + sdst);
  };

  // frag read: logical chunk (k2*4+g) of row -> phys chunk ^(row&7)=^(li&7)
  auto rdfrag = [&](const _Float16* buf, int row, int k2) -> f16x8 {
    const int pc = ((k2 << 2) + g) ^ (li & 7);
    return *(const f16x8*)((const char*)buf + row * 128 + pc * 16);
  };

  f32x4 acc[8][4] = {};

  // ---- prologue: A0(0) B0(0) B1(0) A1(0) A0(1); wait all but newest 3 ----
  stage(gA, Ab[0], 0, 0);
  stage(gB, Bb[0], 0, 0);
  stage(gB, Bb[0], 1, 0);
  stage(gA, Ab[0], 1, 0);
  stage(gA, Ab[1], 0, (NT > 1) ? 64 : 0);
  VMCNT6();
  BAR();

  for (int T = 0; T < NT; ++T) {
    const int cb = T & 1, nb = cb ^ 1;
    const _Float16* Ac = Ab[cb];
    const _Float16* Bc = Bb[cb];
    const int ktN  = (T + 1 < NT) ? (T + 1) << 6 : 0;
    const int ktN2 = (T + 2 < NT) ? (T + 2) << 6 : 0;

    f16x8 af0[4][2], af1[4][2], bf0[2][2], bf1[2][2];

    // ---- p0 ----
#pragma unroll
    for (int m = 0; m < 4; ++m)
#pragma unroll
      for (int k2 = 0; k2 < 2; ++k2)
        af0[m][k2] = rdfrag(Ac, wm * 128 + m * 16 + li, k2);
#pragma unroll
    for (int n = 0; n < 2; ++n)
#pragma unroll
      for (int k2 = 0; k2 < 2; ++k2)
        bf0[n][k2] = rdfrag(Bc, wn * 64 + n * 16 + li, k2);
    stage(gB, Bb[nb], 0, ktN);
    BAR();
    __builtin_amdgcn_s_setprio(1);
#pragma unroll
    for (int m = 0; m < 4; ++m)
#pragma unroll
      for (int n = 0; n < 2; ++n)
#pragma unroll
        for (int k2 = 0; k2 < 2; ++k2)
          acc[m][n] = mfma16x32(af0[m][k2], bf0[n][k2], acc[m][n]);
    __builtin_amdgcn_s_setprio(0);
    VMCNT6();
    BAR();

    // ---- p1 ----
#pragma unroll
    for (int n = 0; n < 2; ++n)
#pragma unroll
      for (int k2 = 0; k2 < 2; ++k2)
        bf1[n][k2] = rdfrag(Bc, wn * 64 + (n + 2) * 16 + li, k2);
    stage(gB, Bb[nb], 1, ktN);
    BAR();
    __builtin_amdgcn_s_setprio(1);
#pragma unroll
    for (int m = 0; m < 4; ++m)
#pragma unroll
      for (int n = 0; n < 2; ++n)
#pragma unroll
        for (int k2 = 0; k2 < 2; ++k2)
          acc[m][n + 2] = mfma16x32(af0[m][k2], bf1[n][k2], acc[m][n + 2]);
    __builtin_amdgcn_s_setprio(0);
    VMCNT6();
    BAR();

    // ---- p2 ----
#pragma unroll
    for (int m = 0; m < 4; ++m)
#pragma unroll
      for (int k2 = 0; k2 < 2; ++k2)
        af1[m][k2] = rdfrag(Ac, wm * 128 + (m + 4) * 16 + li, k2);
    stage(gA, Ab[nb], 1, ktN);
    BAR();
    __builtin_amdgcn_s_setprio(1);
#pragma unroll
    for (int m = 0; m < 4; ++m)
#pragma unroll
      for (int n = 0; n < 2; ++n)
#pragma unroll
        for (int k2 = 0; k2 < 2; ++k2)
          acc[m + 4][n] = mfma16x32(af1[m][k2], bf0[n][k2], acc[m + 4][n]);
    __builtin_amdgcn_s_setprio(0);
    VMCNT6();
    BAR();

    // ---- p3 ----
    stage(gA, Ab[cb], 0, ktN2);   // A0(T+2): same parity buffer as T; its
    BAR();                        // A0 region was last read at p0 of T.
    __builtin_amdgcn_s_setprio(1);
#pragma unroll
    for (int m = 0; m < 4; ++m)
#pragma unroll
      for (int n = 0; n < 2; ++n)
#pragma unroll
        for (int k2 = 0; k2 < 2; ++k2)
          acc[m + 4][n + 2] = mfma16x32(af1[m][k2], bf1[n][k2], acc[m + 4][n + 2]);
    __builtin_amdgcn_s_setprio(0);
    VMCNT6();
    BAR();
  }

  asm volatile("s_waitcnt vmcnt(0)" ::: "memory");  // drain tail garbage loads

  // ---- epilogue: D row = g*4+r, col = li (m89-verified layout) ----
#pragma unroll
  for (int m = 0; m < 8; ++m)
#pragma unroll
    for (int n = 0; n < 4; ++n)
#pragma unroll
      for (int r = 0; r < 4; ++r) {
        const int row = bm + wm * 128 + m * 16 + g * 4 + r;
        const int col = bn + wn * 64 + n * 16 + li;
        C[(size_t)row * N + col] = (OutT)acc[m][n][r];
      }
}

// ---------------- 3. RoPE (2D, grid 16x16, cls offset 1) ----------------
__global__ void rope_kernel(_Float16* __restrict__ qkv,
                            const int* __restrict__ positions) {
  const int idx = blockIdx.x * blockDim.x + threadIdx.x;  // t*512 + hh*16 + ch
  const int ch = idx & 15;          // 16B chunk (4 pairs) within head
  const int hh = (idx >> 4) & 31;   // 0..15 q-heads, 16..31 k-heads
  const int t  = idx >> 9;
  _Float16* p = qkv + (size_t)t * 6144 + hh * 128 + ch * 8;
  const int pos = positions[t];
  f16x8 v = *(const f16x8*)p;
  f16x8 o;
  if (pos == 0) {
#pragma unroll
    for (int u = 0; u < 8; ++u) o[u] = (_Float16)0.f;
  } else {
    const int gi = pos - 1;
    const float tv = (ch < 8) ? (float)(gi >> 4) : (float)(gi & 15);
#pragma unroll
    for (int u = 0; u < 4; ++u) {
      const int k2 = (ch * 4 + u) & 31;
      const float freq = exp2f((float)k2 * (-13.287712379549449f / 32.0f));
      const float ang = tv * freq;
      float s, c;
      sincosf(ang, &s, &c);
      const float x0 = (float)v[2 * u];
      const float x1 = (float)v[2 * u + 1];
      o[2 * u]     = (_Float16)(x0 * c - x1 * s);
      o[2 * u + 1] = (_Float16)(x1 * c + x0 * s);
    }
  }
  *(f16x8*)p = o;
}

// ---------------- 4. causal flash attention ----------------
__global__ void __launch_bounds__(512)
attn_kernel(const _Float16* __restrict__ qkv, _Float16* __restrict__ O) {
  const int b  = blockIdx.x >> 4;
  const int h  = blockIdx.x & 15;
  const int tb = b << 8;
  const int tid = threadIdx.x;
  const int lane = tid & 63;
  const int w = tid >> 6;
  const int g = lane >> 4, li = lane & 15;

  __shared__ __attribute__((aligned(16))) _Float16 Ks[64 * 128];
  __shared__ __attribute__((aligned(16))) _Float16 Vt[128 * 64];
  __shared__ __attribute__((aligned(16))) _Float16 Ps[8][32 * 40];

  f16x8 qf[2][4];
#pragma unroll
  for (int rb = 0; rb < 2; ++rb)
#pragma unroll
    for (int ks = 0; ks < 4; ++ks)
      qf[rb][ks] = *(const f16x8*)(qkv + (size_t)(tb + w * 32 + rb * 16 + li) * 6144
                                   + h * 128 + ks * 32 + g * 8);

  f32x4 oacc[2][8] = {};
  float m_r[2][4], l_r[2][4];
#pragma unroll
  for (int rb = 0; rb < 2; ++rb)
#pragma unroll
    for (int r = 0; r < 4; ++r) { m_r[rb][r] = -1e30f; l_r[rb][r] = 0.f; }

  const float scale = 0.08838834764831845f;  // 1/sqrt(128)

  for (int kt = 0; kt < 4; ++kt) {
#pragma unroll
    for (int i = 0; i < 2; ++i) {
      const int s = i * 512 + tid;
      const int key = s >> 4;
      const int sch = (s & 15) ^ (key & 7);
      const _Float16* gk = qkv + (size_t)(tb + kt * 64 + key) * 6144
                           + 2048 + h * 128 + sch * 8;
      gload16(gk, (char*)Ks + (i * 512 + (tid & ~63)) * 16);
    }
#pragma unroll
    for (int i = 0; i < 2; ++i) {
      const int s = i * 512 + tid;
      const int key = s >> 4;
      const int chv = s & 15;
      f16x8 v = *(const f16x8*)(qkv + (size_t)(tb + kt * 64 + key) * 6144
                                + 4096 + h * 128 + chv * 8);
#pragma unroll
      for (int e = 0; e < 8; ++e) {
        const int d = chv * 8 + e;
        const int blk = ((key >> 3) ^ (d & 7) ^ ((d >> 3) & 7)) & 7;
        Vt[d * 64 + blk * 8 + (key & 7)] = v[e];
      }
    }
    __syncthreads();

    if (kt <= (w >> 1)) {
      f32x4 sacc[2][4] = {};
#pragma unroll
      for (int ks = 0; ks < 4; ++ks) {
        f16x8 kf[4];
#pragma unroll
        for (int cb = 0; cb < 4; ++cb) {
          const int key = cb * 16 + li;
          const int chunk = (ks * 4 + g) ^ (key & 7);
          kf[cb] = *(const f16x8*)((const char*)Ks + key * 256 + chunk * 16);
        }
#pragma unroll
        for (int rb = 0; rb < 2; ++rb)
#pragma unroll
          for (int cb = 0; cb < 4; ++cb)
            sacc[rb][cb] = mfma16x32(qf[rb][ks], kf[cb], sacc[rb][cb]);
      }
#pragma unroll
      for (int rb = 0; rb < 2; ++rb) {
#pragma unroll
        for (int r = 0; r < 4; ++r) {
          const int q = w * 32 + rb * 16 + g * 4 + r;
          float mx = -1e30f;
#pragma unroll
          for (int cb = 0; cb < 4; ++cb) {
            float sv = sacc[rb][cb][r] * scale;
            const int key = kt * 64 + cb * 16 + li;
            sv = (key <= q) ? sv : -1e30f;
            sacc[rb][cb][r] = sv;
            mx = fmaxf(mx, sv);
          }
#pragma unroll
          for (int off = 1; off < 16; off <<= 1)
            mx = fmaxf(mx, __shfl_xor(mx, off));
          const float mold = m_r[rb][r];
          const float mnew = fmaxf(mold, mx);
          const float alpha = exp2f((mold - mnew) * LOG2E);
          float rsum = 0.f;
#pragma unroll
          for (int cb = 0; cb < 4; ++cb) {
            const float pv = exp2f((sacc[rb][cb][r] - mnew) * LOG2E);
            sacc[rb][cb][r] = pv;
            rsum += pv;
          }
#pragma unroll
          for (int off = 1; off < 16; off <<= 1)
            rsum += __shfl_xor(rsum, off);
          m_r[rb][r] = mnew;
          l_r[rb][r] = l_r[rb][r] * alpha + rsum;
#pragma unroll
          for (int db = 0; db < 8; ++db)
            oacc[rb][db][r] *= alpha;
        }
      }
#pragma unroll
      for (int ks2 = 0; ks2 < 2; ++ks2) {
#pragma unroll
        for (int rb = 0; rb < 2; ++rb)
#pragma unroll
          for (int cbh = 0; cbh < 2; ++cbh) {
            const int cb = ks2 * 2 + cbh;
#pragma unroll
            for (int r = 0; r < 4; ++r)
              Ps[w][(rb * 16 + g * 4 + r) * 40 + cbh * 16 + li] =
                  (_Float16)sacc[rb][cb][r];
          }
        asm volatile("s_waitcnt lgkmcnt(0)" ::: "memory");
        f16x8 pa[2];
#pragma unroll
        for (int rb = 0; rb < 2; ++rb)
          pa[rb] = *(const f16x8*)(&Ps[w][(rb * 16 + li) * 40 + g * 8]);
#pragma unroll
        for (int db = 0; db < 8; ++db) {
          const int d = db * 16 + li;
          const int keych = ks2 * 4 + g;
          const int blk = (keych ^ (d & 7) ^ ((d >> 3) & 7)) & 7;
          const f16x8 vf = *(const f16x8*)(&Vt[d * 64 + blk * 8]);
#pragma unroll
          for (int rb = 0; rb < 2; ++rb)
            oacc[rb][db] = mfma16x32(pa[rb], vf, oacc[rb][db]);
        }
      }
    }
    __syncthreads();
  }
#pragma unroll
  for (int rb = 0; rb < 2; ++rb)
#pragma unroll
    for (int db = 0; db < 8; ++db)
#pragma unroll
      for (int r = 0; r < 4; ++r) {
        const int row = tb + w * 32 + rb * 16 + g * 4 + r;
        const int col = h * 128 + db * 16 + li;
        O[(size_t)row * 2048 + col] = (_Float16)(oacc[rb][db][r] / l_r[rb][r]);
      }
}

// ---------------------------------------------------------------------------
extern "C" void kernel_launch(void* const* d_in, const int* in_sizes, int n_in,
                              void* d_out, int out_size, void* d_ws, size_t ws_size,
                              hipStream_t stream) {
  const float* x         = (const float*)d_in[0];
  const int*   positions = (const int*)d_in[1];
  const float* wqkv      = (const float*)d_in[2];
  const float* wo        = (const float*)d_in[3];
  float* out = (float*)d_out;

  char* ws = (char*)d_ws;
  _Float16* qkv    = (_Float16*)(ws);                    // 100663296 B
  _Float16* xf     = (_Float16*)(ws + 100663296);        //  33554432 B
  _Float16* wqkvf  = (_Float16*)(ws + 134217728);        //  25165824 B
  _Float16* wof    = (_Float16*)(ws + 159383552);        //   8388608 B
  _Float16* of     = xf;  // reuse x region for attention output

  cvt_f32_f16<<<16384, 256, 0, stream>>>(x, xf, 4194304);
  cvt_f32_f16<<<12288, 256, 0, stream>>>(wqkv, wqkvf, 3145728);
  cvt_f32_f16<<< 4096, 256, 0, stream>>>(wo, wof, 1048576);

  gemm_bt3<_Float16><<<768, 512, 0, stream>>>(xf, wqkvf, qkv, 8192, 6144, 2048);

  rope_kernel<<<16384, 256, 0, stream>>>(qkv, positions);

  attn_kernel<<<512, 512, 0, stream>>>(qkv, of);

  gemm_bt3<float><<<256, 512, 0, stream>>>(of, wof, out, 8192, 2048, 2048);
}

// Round 4
// 377.816 us; speedup vs baseline: 1.3273x; 1.0114x over previous
//
#include <hip/hip_runtime.h>
#include <cstddef>

// ---------------------------------------------------------------------------
// Fused attention block for MI355X (gfx950), FP16 MFMA pipeline.
// B=32, S=256, DIM=2048, NH=NKV=16, HD=128, GRID=16, BASE=10000, CLS=1.
//
// Pipeline:
//   1. cvt: x, wqkv, wo  f32 -> f16 (ws)
//   2. gemm_bt3<ROPE=true>: qkv = rope(x @ wqkv^T)   (8192x6144x2048, f16)
//      - rope fused in epilogue via __shfl_xor(1) pair exchange
//   3. attn: causal flash attention -> O f16 (8192 x 2048)
//      - wave w owns q-row blocks (w, 15-w): balanced causal work (wall 8->6)
//   4. gemm_bt3<ROPE=false>: out = O @ wo^T          (8192x2048x2048, f32)
//
// gemm_bt3 = m201-style schedule: 256x256 tile, BK=64, 8 waves (2m x 4n),
// 2-deep LDS double buffer (128 KiB), 4 phases/K-tile, 16 MFMA/phase,
// per-phase half-tile staging (stage -> first-use distance = 4 phases),
// counted s_waitcnt vmcnt(6) per phase, XOR chunk swizzle c^(r&7)
// (conflict-free b128), setprio around MFMA, XCD-aware block swizzle.
// ---------------------------------------------------------------------------

typedef float    f32x4 __attribute__((ext_vector_type(4)));
typedef _Float16 f16x8 __attribute__((ext_vector_type(8)));
typedef _Float16 f16x4 __attribute__((ext_vector_type(4)));

#define LOG2E 1.4426950408889634f
#define NLOG2B_32 (-0.41524101186192697f)   // -log2(10000)/32

__device__ static inline f32x4 mfma16x32(f16x8 a, f16x8 b, f32x4 c) {
  return __builtin_amdgcn_mfma_f32_16x16x32_f16(a, b, c, 0, 0, 0);
}

// async global->LDS, 16B per lane; lds must be the wave-uniform base
// (HW dest = base + lane*16).
__device__ static inline void gload16(const void* g, void* lds) {
  __builtin_amdgcn_global_load_lds(
      (const __attribute__((address_space(1))) unsigned int*)g,
      (__attribute__((address_space(3))) unsigned int*)lds, 16, 0, 0);
}

#define BAR()    asm volatile("s_barrier" ::: "memory")
#define VMCNT6() asm volatile("s_waitcnt vmcnt(6)" ::: "memory")

// ---------------- 1. f32 -> f16 convert (vectorized) ----------------
__global__ void cvt_f32_f16(const float* __restrict__ src,
                            _Float16* __restrict__ dst, int n4) {
  int i = blockIdx.x * blockDim.x + threadIdx.x;
  if (i >= n4) return;
  f32x4 v = *(const f32x4*)(src + (size_t)i * 4);
  f16x4 o;
  o[0] = (_Float16)v[0]; o[1] = (_Float16)v[1];
  o[2] = (_Float16)v[2]; o[3] = (_Float16)v[3];
  *(f16x4*)(dst + (size_t)i * 4) = o;
}

// ---------------- 2./4. GEMM: C[m,n] = sum_k A[m,k] * Bt[n,k] ----------------
// Per K-tile (BK=64) 4 phases, per phase one C-quadrant (16 MFMA):
//   p0: read af0(8) bf0(4); stage B0(T+1); MFMA af0 x bf0
//   p1: read bf1(4);        stage B1(T+1); MFMA af0 x bf1
//   p2: read af1(8);        stage A1(T+1); MFMA af1 x bf0
//   p3: (no reads)          stage A0(T+2); MFMA af1 x bf1
// Each phase: reads; stage; BAR; setprio(1); MFMA; setprio(0); vmcnt(6); BAR.
// Gate proof: at each closing vmcnt(6) the 3 newest half-tiles (6 loads) may
// be outstanding; every half-tile a phase reads is >= 4th-newest there.
//
// ROPE epilogue (QKV GEMM only, cols < 4096 = q,k heads): D-frag col = lane
// li, so rope pair (2*d2, 2*d2+1) lives in adjacent lanes; partner via
// __shfl_xor(val,1):  out = val*c + partner*(odd ? s : -s).
// pos = positions[row]; pos==0 -> c=s=0 (zeroed cls row per reference).
template <typename OutT, bool ROPE>
__global__ void __launch_bounds__(512, 2)
gemm_bt3(const _Float16* __restrict__ A, const _Float16* __restrict__ Bt,
         OutT* __restrict__ C, int M, int N, int K,
         const int* __restrict__ positions) {
  __shared__ __attribute__((aligned(16))) _Float16 Ab[2][256 * 64];
  __shared__ __attribute__((aligned(16))) _Float16 Bb[2][256 * 64];

  const int tid  = threadIdx.x;
  const int lane = tid & 63;
  const int w    = tid >> 6;
  const int wm   = w >> 2, wn = w & 3;
  const int g    = lane >> 4, li = lane & 15;

  // T1: XCD-aware block swizzle (grid multiple of 8 for our shapes)
  const int nwg = (int)gridDim.x;
  const int cpx = nwg >> 3;
  const int bid = (int)blockIdx.x;
  const int swz = (bid & 7) * cpx + (bid >> 3);
  const int nbn = N >> 8;
  const int bm  = (swz / nbn) << 8;
  const int bn  = (swz % nbn) << 8;
  const int NT  = K >> 6;

  // ---- staging: half-tile = 128 rows x 64 cols = 1024 chunks of 16B.
  // Thread t, load j covers linear chunk L = j*512 + t  (row L>>3, phys L&7),
  // holding logical chunk (L&7)^((L>>3)&7) -> global col ((t&7)^((t>>3)&7))*8.
  const int srow = tid >> 3;                       // 0..63
  const int scol = ((tid & 7) ^ (srow & 7)) * 8;   // pre-swizzled col (elems)
  const _Float16* gA = A  + (size_t)(bm + srow) * K + scol;
  const _Float16* gB = Bt + (size_t)(bn + srow) * K + scol;
  const int sdst = w * 1024;                       // wave-uniform byte base

  auto stage = [&](const _Float16* gbase, _Float16* lbase, int h, int kt) {
    const _Float16* gp = gbase + (size_t)h * 128 * K + kt;
    char* lp = (char*)lbase + h * 16384;
#pragma unroll
    for (int j = 0; j < 2; ++j)
      gload16(gp + (size_t)j * 64 * K, lp + j * 8192 + sdst);
  };

  // frag read: logical chunk (k2*4+g) of row -> phys chunk ^(row&7)=^(li&7)
  auto rdfrag = [&](const _Float16* buf, int row, int k2) -> f16x8 {
    const int pc = ((k2 << 2) + g) ^ (li & 7);
    return *(const f16x8*)((const char*)buf + row * 128 + pc * 16);
  };

  f32x4 acc[8][4] = {};

  // ---- prologue: A0(0) B0(0) B1(0) A1(0) A0(1); wait all but newest 3 ----
  stage(gA, Ab[0], 0, 0);
  stage(gB, Bb[0], 0, 0);
  stage(gB, Bb[0], 1, 0);
  stage(gA, Ab[0], 1, 0);
  stage(gA, Ab[1], 0, (NT > 1) ? 64 : 0);
  VMCNT6();
  BAR();

  for (int T = 0; T < NT; ++T) {
    const int cb = T & 1, nb = cb ^ 1;
    const _Float16* Ac = Ab[cb];
    const _Float16* Bc = Bb[cb];
    const int ktN  = (T + 1 < NT) ? (T + 1) << 6 : 0;
    const int ktN2 = (T + 2 < NT) ? (T + 2) << 6 : 0;

    f16x8 af0[4][2], af1[4][2], bf0[2][2], bf1[2][2];

    // ---- p0 ----
#pragma unroll
    for (int m = 0; m < 4; ++m)
#pragma unroll
      for (int k2 = 0; k2 < 2; ++k2)
        af0[m][k2] = rdfrag(Ac, wm * 128 + m * 16 + li, k2);
#pragma unroll
    for (int n = 0; n < 2; ++n)
#pragma unroll
      for (int k2 = 0; k2 < 2; ++k2)
        bf0[n][k2] = rdfrag(Bc, wn * 64 + n * 16 + li, k2);
    stage(gB, Bb[nb], 0, ktN);
    BAR();
    __builtin_amdgcn_s_setprio(1);
#pragma unroll
    for (int m = 0; m < 4; ++m)
#pragma unroll
      for (int n = 0; n < 2; ++n)
#pragma unroll
        for (int k2 = 0; k2 < 2; ++k2)
          acc[m][n] = mfma16x32(af0[m][k2], bf0[n][k2], acc[m][n]);
    __builtin_amdgcn_s_setprio(0);
    VMCNT6();
    BAR();

    // ---- p1 ----
#pragma unroll
    for (int n = 0; n < 2; ++n)
#pragma unroll
      for (int k2 = 0; k2 < 2; ++k2)
        bf1[n][k2] = rdfrag(Bc, wn * 64 + (n + 2) * 16 + li, k2);
    stage(gB, Bb[nb], 1, ktN);
    BAR();
    __builtin_amdgcn_s_setprio(1);
#pragma unroll
    for (int m = 0; m < 4; ++m)
#pragma unroll
      for (int n = 0; n < 2; ++n)
#pragma unroll
        for (int k2 = 0; k2 < 2; ++k2)
          acc[m][n + 2] = mfma16x32(af0[m][k2], bf1[n][k2], acc[m][n + 2]);
    __builtin_amdgcn_s_setprio(0);
    VMCNT6();
    BAR();

    // ---- p2 ----
#pragma unroll
    for (int m = 0; m < 4; ++m)
#pragma unroll
      for (int k2 = 0; k2 < 2; ++k2)
        af1[m][k2] = rdfrag(Ac, wm * 128 + (m + 4) * 16 + li, k2);
    stage(gA, Ab[nb], 1, ktN);
    BAR();
    __builtin_amdgcn_s_setprio(1);
#pragma unroll
    for (int m = 0; m < 4; ++m)
#pragma unroll
      for (int n = 0; n < 2; ++n)
#pragma unroll
        for (int k2 = 0; k2 < 2; ++k2)
          acc[m + 4][n] = mfma16x32(af1[m][k2], bf0[n][k2], acc[m + 4][n]);
    __builtin_amdgcn_s_setprio(0);
    VMCNT6();
    BAR();

    // ---- p3 ----
    stage(gA, Ab[cb], 0, ktN2);   // A0(T+2): same parity buffer as T; its
    BAR();                        // A0 region was last read at p0 of T.
    __builtin_amdgcn_s_setprio(1);
#pragma unroll
    for (int m = 0; m < 4; ++m)
#pragma unroll
      for (int n = 0; n < 2; ++n)
#pragma unroll
        for (int k2 = 0; k2 < 2; ++k2)
          acc[m + 4][n + 2] = mfma16x32(af1[m][k2], bf1[n][k2], acc[m + 4][n + 2]);
    __builtin_amdgcn_s_setprio(0);
    VMCNT6();
    BAR();
  }

  asm volatile("s_waitcnt vmcnt(0)" ::: "memory");  // drain tail garbage loads

  // ---- epilogue: D row = g*4+r, col = li (m89-verified layout) ----
  const bool doRope = ROPE && (bn < 4096);
  // per-n frequency (lane-dependent): d2 = ((col>>1)&63), k2f = d2&31
  float freqn[4], half2n[4];
  if (doRope) {
#pragma unroll
    for (int n = 0; n < 4; ++n) {
      const int col = bn + wn * 64 + n * 16 + li;
      const int d2  = (col >> 1) & 63;
      freqn[n]  = exp2f((float)(d2 & 31) * NLOG2B_32);
      half2n[n] = (d2 < 32) ? 1.0f : 0.0f;   // 1 -> use grid row, 0 -> col
    }
  }
#pragma unroll
  for (int m = 0; m < 8; ++m) {
#pragma unroll
    for (int r = 0; r < 4; ++r) {
      const int row = bm + wm * 128 + m * 16 + g * 4 + r;
      float tvA = 0.f, tvB = 0.f;
      bool zero = false;
      if (doRope) {
        const int pos = positions[row];
        zero = (pos == 0);
        const int gi = pos - 1;
        tvA = (float)(gi >> 4);   // grid row
        tvB = (float)(gi & 15);   // grid col
      }
#pragma unroll
      for (int n = 0; n < 4; ++n) {
        float val = acc[m][n][r];
        if (doRope) {
          const float tv  = half2n[n] != 0.f ? tvA : tvB;
          float s, c;
          __sincosf(tv * freqn[n], &s, &c);
          if (zero) { s = 0.f; c = 0.f; }
          const float partner = __shfl_xor(val, 1);
          val = val * c + partner * ((li & 1) ? s : -s);
        }
        const int col = bn + wn * 64 + n * 16 + li;
        C[(size_t)row * N + col] = (OutT)val;
      }
    }
  }
}

// ---------------- 3. causal flash attention ----------------
// 1 block = 1 (b,h), 512 threads = 8 waves. Wave w owns TWO 16-row q-blocks:
// qb0 = w, qb1 = 15-w  -> every wave has exactly 5 sub-tile compute units,
// per-kt wall 2+2+1+1 = 6 (vs 8 for contiguous 32-row ownership).
// K-tiles of 64 keys staged in LDS (all waves):
//   Ks: row-major [64][128], 16B chunks XOR-swizzled (chunk ^= key&7) via
//       pre-swizzled global source (global_load_lds writes linearly).
//   Vt: transposed [d][key], chunk swizzle blk = (key>>3)^(d&7)^((d>>3)&7).
//   Ps: per-wave P round-trip (D-frag layout -> A-frag layout), stride 40.
__global__ void __launch_bounds__(512)
attn_kernel(const _Float16* __restrict__ qkv, _Float16* __restrict__ O) {
  const int b  = blockIdx.x >> 4;
  const int h  = blockIdx.x & 15;
  const int tb = b << 8;
  const int tid = threadIdx.x;
  const int lane = tid & 63;
  const int w = tid >> 6;
  const int g = lane >> 4, li = lane & 15;

  __shared__ __attribute__((aligned(16))) _Float16 Ks[64 * 128];
  __shared__ __attribute__((aligned(16))) _Float16 Vt[128 * 64];
  __shared__ __attribute__((aligned(16))) _Float16 Ps[8][32 * 40];

  const int qb[2]   = {w, 15 - w};
  const int qrow[2] = {qb[0] * 16, qb[1] * 16};
  const int kmax[2] = {qb[0] >> 2, qb[1] >> 2};

  f16x8 qf[2][4];
#pragma unroll
  for (int rb = 0; rb < 2; ++rb)
#pragma unroll
    for (int ks = 0; ks < 4; ++ks)
      qf[rb][ks] = *(const f16x8*)(qkv + (size_t)(tb + qrow[rb] + li) * 6144
                                   + h * 128 + ks * 32 + g * 8);

  f32x4 oacc[2][8] = {};
  float m_r[2][4], l_r[2][4];
#pragma unroll
  for (int rb = 0; rb < 2; ++rb)
#pragma unroll
    for (int r = 0; r < 4; ++r) { m_r[rb][r] = -1e30f; l_r[rb][r] = 0.f; }

  const float scale = 0.08838834764831845f;  // 1/sqrt(128)

  for (int kt = 0; kt < 4; ++kt) {
    // ---- stage K tile ----
#pragma unroll
    for (int i = 0; i < 2; ++i) {
      const int s = i * 512 + tid;
      const int key = s >> 4;
      const int sch = (s & 15) ^ (key & 7);
      const _Float16* gk = qkv + (size_t)(tb + kt * 64 + key) * 6144
                           + 2048 + h * 128 + sch * 8;
      gload16(gk, (char*)Ks + (i * 512 + (tid & ~63)) * 16);
    }
    // ---- stage V transposed + swizzled via registers ----
#pragma unroll
    for (int i = 0; i < 2; ++i) {
      const int s = i * 512 + tid;
      const int key = s >> 4;
      const int chv = s & 15;
      f16x8 v = *(const f16x8*)(qkv + (size_t)(tb + kt * 64 + key) * 6144
                                + 4096 + h * 128 + chv * 8);
#pragma unroll
      for (int e = 0; e < 8; ++e) {
        const int d = chv * 8 + e;
        const int blk = ((key >> 3) ^ (d & 7) ^ ((d >> 3) & 7)) & 7;
        Vt[d * 64 + blk * 8 + (key & 7)] = v[e];
      }
    }
    __syncthreads();

    const bool act[2] = {kt <= kmax[0], kt <= kmax[1]};
    if (act[0] || act[1]) {
      // ---- S = Q K^T (64 keys) ----
      f32x4 sacc[2][4] = {};
#pragma unroll
      for (int ks = 0; ks < 4; ++ks) {
        f16x8 kf[4];
#pragma unroll
        for (int cb = 0; cb < 4; ++cb) {
          const int key = cb * 16 + li;
          const int chunk = (ks * 4 + g) ^ (key & 7);
          kf[cb] = *(const f16x8*)((const char*)Ks + key * 256 + chunk * 16);
        }
#pragma unroll
        for (int rb = 0; rb < 2; ++rb)
          if (act[rb])
#pragma unroll
            for (int cb = 0; cb < 4; ++cb)
              sacc[rb][cb] = mfma16x32(qf[rb][ks], kf[cb], sacc[rb][cb]);
      }
      // ---- online softmax (wave-parallel, 16-lane-group shfl reduce) ----
#pragma unroll
      for (int rb = 0; rb < 2; ++rb) {
        if (!act[rb]) continue;
#pragma unroll
        for (int r = 0; r < 4; ++r) {
          const int q = qrow[rb] + g * 4 + r;
          float mx = -1e30f;
#pragma unroll
          for (int cb = 0; cb < 4; ++cb) {
            float sv = sacc[rb][cb][r] * scale;
            const int key = kt * 64 + cb * 16 + li;
            sv = (key <= q) ? sv : -1e30f;
            sacc[rb][cb][r] = sv;
            mx = fmaxf(mx, sv);
          }
#pragma unroll
          for (int off = 1; off < 16; off <<= 1)
            mx = fmaxf(mx, __shfl_xor(mx, off));
          const float mold = m_r[rb][r];
          const float mnew = fmaxf(mold, mx);
          const float alpha = exp2f((mold - mnew) * LOG2E);
          float rsum = 0.f;
#pragma unroll
          for (int cb = 0; cb < 4; ++cb) {
            const float pv = exp2f((sacc[rb][cb][r] - mnew) * LOG2E);
            sacc[rb][cb][r] = pv;
            rsum += pv;
          }
#pragma unroll
          for (int off = 1; off < 16; off <<= 1)
            rsum += __shfl_xor(rsum, off);
          m_r[rb][r] = mnew;
          l_r[rb][r] = l_r[rb][r] * alpha + rsum;
#pragma unroll
          for (int db = 0; db < 8; ++db)
            oacc[rb][db][r] *= alpha;
        }
      }
      // ---- O += P V, in two 32-key halves (P relayout via per-wave LDS) ----
#pragma unroll
      for (int ks2 = 0; ks2 < 2; ++ks2) {
#pragma unroll
        for (int rb = 0; rb < 2; ++rb) {
          if (!act[rb]) continue;
#pragma unroll
          for (int cbh = 0; cbh < 2; ++cbh) {
            const int cb = ks2 * 2 + cbh;
#pragma unroll
            for (int r = 0; r < 4; ++r)
              Ps[w][(rb * 16 + g * 4 + r) * 40 + cbh * 16 + li] =
                  (_Float16)sacc[rb][cb][r];
          }
        }
        asm volatile("s_waitcnt lgkmcnt(0)" ::: "memory");
        f16x8 pa[2];
#pragma unroll
        for (int rb = 0; rb < 2; ++rb)
          if (act[rb])
            pa[rb] = *(const f16x8*)(&Ps[w][(rb * 16 + li) * 40 + g * 8]);
#pragma unroll
        for (int db = 0; db < 8; ++db) {
          const int d = db * 16 + li;
          const int keych = ks2 * 4 + g;
          const int blk = (keych ^ (d & 7) ^ ((d >> 3) & 7)) & 7;
          const f16x8 vf = *(const f16x8*)(&Vt[d * 64 + blk * 8]);
#pragma unroll
          for (int rb = 0; rb < 2; ++rb)
            if (act[rb])
              oacc[rb][db] = mfma16x32(pa[rb], vf, oacc[rb][db]);
        }
      }
    }
    __syncthreads();
  }
  // ---- epilogue: O / l ----
#pragma unroll
  for (int rb = 0; rb < 2; ++rb)
#pragma unroll
    for (int db = 0; db < 8; ++db)
#pragma unroll
      for (int r = 0; r < 4; ++r) {
        const int row = tb + qrow[rb] + g * 4 + r;
        const int col = h * 128 + db * 16 + li;
        O[(size_t)row * 2048 + col] = (_Float16)(oacc[rb][db][r] / l_r[rb][r]);
      }
}

// ---------------------------------------------------------------------------
extern "C" void kernel_launch(void* const* d_in, const int* in_sizes, int n_in,
                              void* d_out, int out_size, void* d_ws, size_t ws_size,
                              hipStream_t stream) {
  const float* x         = (const float*)d_in[0];
  const int*   positions = (const int*)d_in[1];
  const float* wqkv      = (const float*)d_in[2];
  const float* wo        = (const float*)d_in[3];
  float* out = (float*)d_out;

  char* ws = (char*)d_ws;
  _Float16* qkv    = (_Float16*)(ws);                    // 100663296 B
  _Float16* xf     = (_Float16*)(ws + 100663296);        //  33554432 B
  _Float16* wqkvf  = (_Float16*)(ws + 134217728);        //  25165824 B
  _Float16* wof    = (_Float16*)(ws + 159383552);        //   8388608 B
  _Float16* of     = xf;  // reuse x region for attention output

  cvt_f32_f16<<<16384, 256, 0, stream>>>(x, xf, 4194304);
  cvt_f32_f16<<<12288, 256, 0, stream>>>(wqkv, wqkvf, 3145728);
  cvt_f32_f16<<< 4096, 256, 0, stream>>>(wo, wof, 1048576);

  gemm_bt3<_Float16, true><<<768, 512, 0, stream>>>(
      xf, wqkvf, qkv, 8192, 6144, 2048, positions);

  attn_kernel<<<512, 512, 0, stream>>>(qkv, of);

  gemm_bt3<float, false><<<256, 512, 0, stream>>>(
      of, wof, out, 8192, 2048, 2048, nullptr);
}

// Round 5
// 374.187 us; speedup vs baseline: 1.3402x; 1.0097x over previous
//
#include <hip/hip_runtime.h>
#include <cstddef>

// ---------------------------------------------------------------------------
// Fused attention block for MI355X (gfx950), FP16 MFMA pipeline.
// B=32, S=256, DIM=2048, NH=NKV=16, HD=128, GRID=16, BASE=10000, CLS=1.
//
// Pipeline:
//   1. cvt3: x, wqkv, wo  f32 -> f16 (single kernel)
//   2. gemm_bt3<ROPE=true>: qkv = rope(x @ wqkv^T)   (8192x6144x2048, f16)
//      - rope fused in epilogue; 512-entry LDS sincos table (tv in 0..15 x
//        32 freqs) + LDS-staged positions; pair exchange via __shfl_xor(1)
//   3. attn: causal flash attention -> O f16 (8192 x 2048)
//      - wave w owns q-row blocks (w, 15-w): balanced causal work (wall 8->6)
//   4. gemm_bt3<ROPE=false>: out = O @ wo^T          (8192x2048x2048, f32)
//
// gemm_bt3 = m201-style schedule: 256x256 tile, BK=64, 8 waves (2m x 4n),
// 2-deep LDS double buffer (128 KiB), 4 phases/K-tile, 16 MFMA/phase,
// per-phase half-tile staging (stage -> first-use distance = 4 phases),
// counted s_waitcnt vmcnt(6) per phase, XOR chunk swizzle c^(r&7)
// (conflict-free b128), setprio around MFMA, XCD-aware block swizzle.
// ---------------------------------------------------------------------------

typedef float    f32x4 __attribute__((ext_vector_type(4)));
typedef _Float16 f16x8 __attribute__((ext_vector_type(8)));
typedef _Float16 f16x4 __attribute__((ext_vector_type(4)));

#define LOG2E 1.4426950408889634f
#define NLOG2B_32 (-0.41524101186192697f)   // -log2(10000)/32

__device__ static inline f32x4 mfma16x32(f16x8 a, f16x8 b, f32x4 c) {
  return __builtin_amdgcn_mfma_f32_16x16x32_f16(a, b, c, 0, 0, 0);
}

// async global->LDS, 16B per lane; lds must be the wave-uniform base
// (HW dest = base + lane*16).
__device__ static inline void gload16(const void* g, void* lds) {
  __builtin_amdgcn_global_load_lds(
      (const __attribute__((address_space(1))) unsigned int*)g,
      (__attribute__((address_space(3))) unsigned int*)lds, 16, 0, 0);
}

#define BAR()    asm volatile("s_barrier" ::: "memory")
#define VMCNT6() asm volatile("s_waitcnt vmcnt(6)" ::: "memory")

// ---------------- 1. f32 -> f16 convert (three buffers, one kernel) --------
__global__ void cvt3_f32_f16(const float* __restrict__ s0, _Float16* __restrict__ d0,
                             const float* __restrict__ s1, _Float16* __restrict__ d1,
                             const float* __restrict__ s2, _Float16* __restrict__ d2) {
  int i = blockIdx.x * blockDim.x + threadIdx.x;   // quad index
  const float* src; _Float16* dst;
  if (i < 4194304)      { src = s0; dst = d0; }
  else if (i < 7340032) { src = s1; dst = d1; i -= 4194304; }
  else                  { src = s2; dst = d2; i -= 7340032; }
  f32x4 v = *(const f32x4*)(src + (size_t)i * 4);
  f16x4 o;
  o[0] = (_Float16)v[0]; o[1] = (_Float16)v[1];
  o[2] = (_Float16)v[2]; o[3] = (_Float16)v[3];
  *(f16x4*)(dst + (size_t)i * 4) = o;
}

// ---------------- 2./4. GEMM: C[m,n] = sum_k A[m,k] * Bt[n,k] ----------------
// Per K-tile (BK=64) 4 phases, per phase one C-quadrant (16 MFMA):
//   p0: read af0(8) bf0(4); stage B0(T+1); MFMA af0 x bf0
//   p1: read bf1(4);        stage B1(T+1); MFMA af0 x bf1
//   p2: read af1(8);        stage A1(T+1); MFMA af1 x bf0
//   p3: (no reads)          stage A0(T+2); MFMA af1 x bf1
// Each phase: reads; stage; BAR; setprio(1); MFMA; setprio(0); vmcnt(6); BAR.
// Gate proof: at each closing vmcnt(6) the 3 newest half-tiles (6 loads) may
// be outstanding; every half-tile a phase reads is >= 4th-newest there.
//
// ROPE epilogue (QKV GEMM, cols < 4096 = q,k heads): D-frag col = lane li,
// so rope pair (2*d2, 2*d2+1) lives in adjacent lanes; partner via
// __shfl_xor(val,1):  out = val*c + partner*(odd ? s : -s).
// cos/sin from 512-entry LDS table (tv*32 + k2); pos==0 -> c=s=0 (cls row).
template <typename OutT, bool ROPE>
__global__ void __launch_bounds__(512, 2)
gemm_bt3(const _Float16* __restrict__ A, const _Float16* __restrict__ Bt,
         OutT* __restrict__ C, int M, int N, int K,
         const int* __restrict__ positions) {
  __shared__ __attribute__((aligned(16))) _Float16 Ab[2][256 * 64];
  __shared__ __attribute__((aligned(16))) _Float16 Bb[2][256 * 64];
  __shared__ float2 tab[512];
  __shared__ int    ptab[256];

  const int tid  = threadIdx.x;
  const int lane = tid & 63;
  const int w    = tid >> 6;
  const int wm   = w >> 2, wn = w & 3;
  const int g    = lane >> 4, li = lane & 15;

  // T1: XCD-aware block swizzle (grid multiple of 8 for our shapes)
  const int nwg = (int)gridDim.x;
  const int cpx = nwg >> 3;
  const int bid = (int)blockIdx.x;
  const int swz = (bid & 7) * cpx + (bid >> 3);
  const int nbn = N >> 8;
  const int bm  = (swz / nbn) << 8;
  const int bn  = (swz % nbn) << 8;
  const int NT  = K >> 6;

  if (ROPE) {
    // sincos table: tv = tid>>5 (0..15), k2 = tid&31
    const float ang = (float)(tid >> 5) * exp2f((float)(tid & 31) * NLOG2B_32);
    tab[tid] = make_float2(cosf(ang), sinf(ang));
    if (tid < 256) ptab[tid] = positions[bm + tid];
    __syncthreads();
  }

  // ---- staging: half-tile = 128 rows x 64 cols = 1024 chunks of 16B.
  // Thread t, load j covers linear chunk L = j*512 + t  (row L>>3, phys L&7),
  // holding logical chunk (L&7)^((L>>3)&7) -> global col ((t&7)^((t>>3)&7))*8.
  const int srow = tid >> 3;                       // 0..63
  const int scol = ((tid & 7) ^ (srow & 7)) * 8;   // pre-swizzled col (elems)
  const _Float16* gA = A  + (size_t)(bm + srow) * K + scol;
  const _Float16* gB = Bt + (size_t)(bn + srow) * K + scol;
  const int sdst = w * 1024;                       // wave-uniform byte base

  auto stage = [&](const _Float16* gbase, _Float16* lbase, int h, int kt) {
    const _Float16* gp = gbase + (size_t)h * 128 * K + kt;
    char* lp = (char*)lbase + h * 16384;
#pragma unroll
    for (int j = 0; j < 2; ++j)
      gload16(gp + (size_t)j * 64 * K, lp + j * 8192 + sdst);
  };

  // frag read: logical chunk (k2*4+g) of row -> phys chunk ^(row&7)=^(li&7)
  auto rdfrag = [&](const _Float16* buf, int row, int k2) -> f16x8 {
    const int pc = ((k2 << 2) + g) ^ (li & 7);
    return *(const f16x8*)((const char*)buf + row * 128 + pc * 16);
  };

  f32x4 acc[8][4] = {};

  // ---- prologue: A0(0) B0(0) B1(0) A1(0) A0(1); wait all but newest 3 ----
  stage(gA, Ab[0], 0, 0);
  stage(gB, Bb[0], 0, 0);
  stage(gB, Bb[0], 1, 0);
  stage(gA, Ab[0], 1, 0);
  stage(gA, Ab[1], 0, (NT > 1) ? 64 : 0);
  VMCNT6();
  BAR();

  for (int T = 0; T < NT; ++T) {
    const int cb = T & 1, nb = cb ^ 1;
    const _Float16* Ac = Ab[cb];
    const _Float16* Bc = Bb[cb];
    const int ktN  = (T + 1 < NT) ? (T + 1) << 6 : 0;
    const int ktN2 = (T + 2 < NT) ? (T + 2) << 6 : 0;

    f16x8 af0[4][2], af1[4][2], bf0[2][2], bf1[2][2];

    // ---- p0 ----
#pragma unroll
    for (int m = 0; m < 4; ++m)
#pragma unroll
      for (int k2 = 0; k2 < 2; ++k2)
        af0[m][k2] = rdfrag(Ac, wm * 128 + m * 16 + li, k2);
#pragma unroll
    for (int n = 0; n < 2; ++n)
#pragma unroll
      for (int k2 = 0; k2 < 2; ++k2)
        bf0[n][k2] = rdfrag(Bc, wn * 64 + n * 16 + li, k2);
    stage(gB, Bb[nb], 0, ktN);
    BAR();
    __builtin_amdgcn_s_setprio(1);
#pragma unroll
    for (int m = 0; m < 4; ++m)
#pragma unroll
      for (int n = 0; n < 2; ++n)
#pragma unroll
        for (int k2 = 0; k2 < 2; ++k2)
          acc[m][n] = mfma16x32(af0[m][k2], bf0[n][k2], acc[m][n]);
    __builtin_amdgcn_s_setprio(0);
    VMCNT6();
    BAR();

    // ---- p1 ----
#pragma unroll
    for (int n = 0; n < 2; ++n)
#pragma unroll
      for (int k2 = 0; k2 < 2; ++k2)
        bf1[n][k2] = rdfrag(Bc, wn * 64 + (n + 2) * 16 + li, k2);
    stage(gB, Bb[nb], 1, ktN);
    BAR();
    __builtin_amdgcn_s_setprio(1);
#pragma unroll
    for (int m = 0; m < 4; ++m)
#pragma unroll
      for (int n = 0; n < 2; ++n)
#pragma unroll
        for (int k2 = 0; k2 < 2; ++k2)
          acc[m][n + 2] = mfma16x32(af0[m][k2], bf1[n][k2], acc[m][n + 2]);
    __builtin_amdgcn_s_setprio(0);
    VMCNT6();
    BAR();

    // ---- p2 ----
#pragma unroll
    for (int m = 0; m < 4; ++m)
#pragma unroll
      for (int k2 = 0; k2 < 2; ++k2)
        af1[m][k2] = rdfrag(Ac, wm * 128 + (m + 4) * 16 + li, k2);
    stage(gA, Ab[nb], 1, ktN);
    BAR();
    __builtin_amdgcn_s_setprio(1);
#pragma unroll
    for (int m = 0; m < 4; ++m)
#pragma unroll
      for (int n = 0; n < 2; ++n)
#pragma unroll
        for (int k2 = 0; k2 < 2; ++k2)
          acc[m + 4][n] = mfma16x32(af1[m][k2], bf0[n][k2], acc[m + 4][n]);
    __builtin_amdgcn_s_setprio(0);
    VMCNT6();
    BAR();

    // ---- p3 ----
    stage(gA, Ab[cb], 0, ktN2);   // A0(T+2): same parity buffer as T; its
    BAR();                        // A0 region was last read at p0 of T.
    __builtin_amdgcn_s_setprio(1);
#pragma unroll
    for (int m = 0; m < 4; ++m)
#pragma unroll
      for (int n = 0; n < 2; ++n)
#pragma unroll
        for (int k2 = 0; k2 < 2; ++k2)
          acc[m + 4][n + 2] = mfma16x32(af1[m][k2], bf1[n][k2], acc[m + 4][n + 2]);
    __builtin_amdgcn_s_setprio(0);
    VMCNT6();
    BAR();
  }

  asm volatile("s_waitcnt vmcnt(0)" ::: "memory");  // drain tail garbage loads

  // ---- epilogue: D row = g*4+r, col = li (m89-verified layout) ----
  const bool doRope = ROPE && (bn < 4096);
  int k2n[4], halfn[4];
  if (doRope) {
#pragma unroll
    for (int n = 0; n < 4; ++n) {
      const int col = bn + wn * 64 + n * 16 + li;
      const int d2  = (col >> 1) & 63;
      k2n[n]   = d2 & 31;
      halfn[n] = (d2 < 32);
    }
  }
  const float sgn = (li & 1) ? 1.0f : -1.0f;
#pragma unroll
  for (int m = 0; m < 8; ++m) {
#pragma unroll
    for (int r = 0; r < 4; ++r) {
      const int rloc = wm * 128 + m * 16 + g * 4 + r;
      const int row  = bm + rloc;
      int tvA = 0, tvB = 0;
      bool zero = false;
      if (doRope) {
        const int pos = ptab[rloc];
        zero = (pos == 0);
        const int gi = pos - 1;
        tvA = (gi >> 4) & 15;
        tvB = gi & 15;
      }
#pragma unroll
      for (int n = 0; n < 4; ++n) {
        float val = acc[m][n][r];
        if (doRope) {
          const int tv = halfn[n] ? tvA : tvB;
          const float2 cs = tab[tv * 32 + k2n[n]];
          const float c = zero ? 0.f : cs.x;
          const float s = zero ? 0.f : cs.y;
          const float partner = __shfl_xor(val, 1);
          val = val * c + partner * (sgn * s);
        }
        const int col = bn + wn * 64 + n * 16 + li;
        C[(size_t)row * N + col] = (OutT)val;
      }
    }
  }
}

// ---------------- 3. causal flash attention ----------------
// 1 block = 1 (b,h), 512 threads = 8 waves. Wave w owns TWO 16-row q-blocks:
// qb0 = w, qb1 = 15-w  -> every wave has exactly 5 sub-tile compute units,
// per-kt wall 2+2+1+1 = 6 (vs 8 for contiguous 32-row ownership).
// K-tiles of 64 keys staged in LDS (all waves):
//   Ks: row-major [64][128], 16B chunks XOR-swizzled (chunk ^= key&7) via
//       pre-swizzled global source (global_load_lds writes linearly).
//   Vt: transposed [d][key], chunk swizzle blk = (key>>3)^(d&7)^((d>>3)&7).
//   Ps: per-wave P round-trip (D-frag layout -> A-frag layout), stride 40.
__global__ void __launch_bounds__(512)
attn_kernel(const _Float16* __restrict__ qkv, _Float16* __restrict__ O) {
  const int b  = blockIdx.x >> 4;
  const int h  = blockIdx.x & 15;
  const int tb = b << 8;
  const int tid = threadIdx.x;
  const int lane = tid & 63;
  const int w = tid >> 6;
  const int g = lane >> 4, li = lane & 15;

  __shared__ __attribute__((aligned(16))) _Float16 Ks[64 * 128];
  __shared__ __attribute__((aligned(16))) _Float16 Vt[128 * 64];
  __shared__ __attribute__((aligned(16))) _Float16 Ps[8][32 * 40];

  const int qb[2]   = {w, 15 - w};
  const int qrow[2] = {qb[0] * 16, qb[1] * 16};
  const int kmax[2] = {qb[0] >> 2, qb[1] >> 2};

  f16x8 qf[2][4];
#pragma unroll
  for (int rb = 0; rb < 2; ++rb)
#pragma unroll
    for (int ks = 0; ks < 4; ++ks)
      qf[rb][ks] = *(const f16x8*)(qkv + (size_t)(tb + qrow[rb] + li) * 6144
                                   + h * 128 + ks * 32 + g * 8);

  f32x4 oacc[2][8] = {};
  float m_r[2][4], l_r[2][4];
#pragma unroll
  for (int rb = 0; rb < 2; ++rb)
#pragma unroll
    for (int r = 0; r < 4; ++r) { m_r[rb][r] = -1e30f; l_r[rb][r] = 0.f; }

  const float scale = 0.08838834764831845f;  // 1/sqrt(128)

  for (int kt = 0; kt < 4; ++kt) {
    // ---- stage K tile ----
#pragma unroll
    for (int i = 0; i < 2; ++i) {
      const int s = i * 512 + tid;
      const int key = s >> 4;
      const int sch = (s & 15) ^ (key & 7);
      const _Float16* gk = qkv + (size_t)(tb + kt * 64 + key) * 6144
                           + 2048 + h * 128 + sch * 8;
      gload16(gk, (char*)Ks + (i * 512 + (tid & ~63)) * 16);
    }
    // ---- stage V transposed + swizzled via registers ----
#pragma unroll
    for (int i = 0; i < 2; ++i) {
      const int s = i * 512 + tid;
      const int key = s >> 4;
      const int chv = s & 15;
      f16x8 v = *(const f16x8*)(qkv + (size_t)(tb + kt * 64 + key) * 6144
                                + 4096 + h * 128 + chv * 8);
#pragma unroll
      for (int e = 0; e < 8; ++e) {
        const int d = chv * 8 + e;
        const int blk = ((key >> 3) ^ (d & 7) ^ ((d >> 3) & 7)) & 7;
        Vt[d * 64 + blk * 8 + (key & 7)] = v[e];
      }
    }
    __syncthreads();

    const bool act[2] = {kt <= kmax[0], kt <= kmax[1]};
    if (act[0] || act[1]) {
      // ---- S = Q K^T (64 keys) ----
      f32x4 sacc[2][4] = {};
#pragma unroll
      for (int ks = 0; ks < 4; ++ks) {
        f16x8 kf[4];
#pragma unroll
        for (int cb = 0; cb < 4; ++cb) {
          const int key = cb * 16 + li;
          const int chunk = (ks * 4 + g) ^ (key & 7);
          kf[cb] = *(const f16x8*)((const char*)Ks + key * 256 + chunk * 16);
        }
#pragma unroll
        for (int rb = 0; rb < 2; ++rb)
          if (act[rb])
#pragma unroll
            for (int cb = 0; cb < 4; ++cb)
              sacc[rb][cb] = mfma16x32(qf[rb][ks], kf[cb], sacc[rb][cb]);
      }
      // ---- online softmax (wave-parallel, 16-lane-group shfl reduce) ----
#pragma unroll
      for (int rb = 0; rb < 2; ++rb) {
        if (!act[rb]) continue;
#pragma unroll
        for (int r = 0; r < 4; ++r) {
          const int q = qrow[rb] + g * 4 + r;
          float mx = -1e30f;
#pragma unroll
          for (int cb = 0; cb < 4; ++cb) {
            float sv = sacc[rb][cb][r] * scale;
            const int key = kt * 64 + cb * 16 + li;
            sv = (key <= q) ? sv : -1e30f;
            sacc[rb][cb][r] = sv;
            mx = fmaxf(mx, sv);
          }
#pragma unroll
          for (int off = 1; off < 16; off <<= 1)
            mx = fmaxf(mx, __shfl_xor(mx, off));
          const float mold = m_r[rb][r];
          const float mnew = fmaxf(mold, mx);
          const float alpha = exp2f((mold - mnew) * LOG2E);
          float rsum = 0.f;
#pragma unroll
          for (int cb = 0; cb < 4; ++cb) {
            const float pv = exp2f((sacc[rb][cb][r] - mnew) * LOG2E);
            sacc[rb][cb][r] = pv;
            rsum += pv;
          }
#pragma unroll
          for (int off = 1; off < 16; off <<= 1)
            rsum += __shfl_xor(rsum, off);
          m_r[rb][r] = mnew;
          l_r[rb][r] = l_r[rb][r] * alpha + rsum;
#pragma unroll
          for (int db = 0; db < 8; ++db)
            oacc[rb][db][r] *= alpha;
        }
      }
      // ---- O += P V, in two 32-key halves (P relayout via per-wave LDS) ----
#pragma unroll
      for (int ks2 = 0; ks2 < 2; ++ks2) {
#pragma unroll
        for (int rb = 0; rb < 2; ++rb) {
          if (!act[rb]) continue;
#pragma unroll
          for (int cbh = 0; cbh < 2; ++cbh) {
            const int cb = ks2 * 2 + cbh;
#pragma unroll
            for (int r = 0; r < 4; ++r)
              Ps[w][(rb * 16 + g * 4 + r) * 40 + cbh * 16 + li] =
                  (_Float16)sacc[rb][cb][r];
          }
        }
        asm volatile("s_waitcnt lgkmcnt(0)" ::: "memory");
        f16x8 pa[2];
#pragma unroll
        for (int rb = 0; rb < 2; ++rb)
          if (act[rb])
            pa[rb] = *(const f16x8*)(&Ps[w][(rb * 16 + li) * 40 + g * 8]);
#pragma unroll
        for (int db = 0; db < 8; ++db) {
          const int d = db * 16 + li;
          const int keych = ks2 * 4 + g;
          const int blk = (keych ^ (d & 7) ^ ((d >> 3) & 7)) & 7;
          const f16x8 vf = *(const f16x8*)(&Vt[d * 64 + blk * 8]);
#pragma unroll
          for (int rb = 0; rb < 2; ++rb)
            if (act[rb])
              oacc[rb][db] = mfma16x32(pa[rb], vf, oacc[rb][db]);
        }
      }
    }
    __syncthreads();
  }
  // ---- epilogue: O / l ----
#pragma unroll
  for (int rb = 0; rb < 2; ++rb)
#pragma unroll
    for (int db = 0; db < 8; ++db)
#pragma unroll
      for (int r = 0; r < 4; ++r) {
        const int row = tb + qrow[rb] + g * 4 + r;
        const int col = h * 128 + db * 16 + li;
        O[(size_t)row * 2048 + col] = (_Float16)(oacc[rb][db][r] / l_r[rb][r]);
      }
}

// ---------------------------------------------------------------------------
extern "C" void kernel_launch(void* const* d_in, const int* in_sizes, int n_in,
                              void* d_out, int out_size, void* d_ws, size_t ws_size,
                              hipStream_t stream) {
  const float* x         = (const float*)d_in[0];
  const int*   positions = (const int*)d_in[1];
  const float* wqkv      = (const float*)d_in[2];
  const float* wo        = (const float*)d_in[3];
  float* out = (float*)d_out;

  char* ws = (char*)d_ws;
  _Float16* qkv    = (_Float16*)(ws);                    // 100663296 B
  _Float16* xf     = (_Float16*)(ws + 100663296);        //  33554432 B
  _Float16* wqkvf  = (_Float16*)(ws + 134217728);        //  25165824 B
  _Float16* wof    = (_Float16*)(ws + 159383552);        //   8388608 B
  _Float16* of     = xf;  // reuse x region for attention output

  cvt3_f32_f16<<<32768, 256, 0, stream>>>(x, xf, wqkv, wqkvf, wo, wof);

  gemm_bt3<_Float16, true><<<768, 512, 0, stream>>>(
      xf, wqkvf, qkv, 8192, 6144, 2048, positions);

  attn_kernel<<<512, 512, 0, stream>>>(qkv, of);

  gemm_bt3<float, false><<<256, 512, 0, stream>>>(
      of, wof, out, 8192, 2048, 2048, nullptr);
}